// Round 7
// baseline (383.613 us; speedup 1.0000x reference)
//
#include <hip/hip_runtime.h>
#include <math.h>

#define BS 32
#define S  2048
#define H  1024
#define ROWS_PB 8   // rows of enc per scores-block: 8 x 4 KiB = 32 KiB LDS tile

typedef __attribute__((address_space(1))) void gvoid;
typedef __attribute__((address_space(3))) void lvoid;

// async global->LDS DMA, 16B per lane, no destination VGPRs.
// lds dest is wave-uniform base + lane*16 (hardware rule).
__device__ __forceinline__ void load16_to_lds(const void* g, void* l) {
    __builtin_amdgcn_global_load_lds((gvoid*)(uintptr_t)g, (lvoid*)l, 16, 0, 0);
}

// ---------------------------------------------------------------------------
// Kernel 1: v[b,h] = sum_k hidden[b,k] * W[k,h]   (v = hidden @ W)
// grid (H/64, BS) = 512 blocks, block 256 = 4 waves. Split-k across waves;
// LDS combine. W (4 MiB) is L2/LLC-resident.
// ---------------------------------------------------------------------------
__global__ __launch_bounds__(256) void compute_v(const float* __restrict__ hidden,
                                                 const float* __restrict__ W,
                                                 float* __restrict__ v) {
    __shared__ float hid[H];
    __shared__ float part[4][64];
    const int b    = blockIdx.y;
    const int tid  = threadIdx.x;
    const int wave = tid >> 6;
    const int lane = tid & 63;

    ((float4*)hid)[tid] = ((const float4*)(hidden + b * H))[tid];
    __syncthreads();

    const int h = blockIdx.x * 64 + lane;
    const float* Wp = W + (size_t)(wave * 256) * H + h;
    const float* hp = hid + wave * 256;
    float acc = 0.f;
#pragma unroll 8
    for (int k = 0; k < 256; ++k)
        acc = fmaf(Wp[(size_t)k * H], hp[k], acc);

    part[wave][lane] = acc;
    __syncthreads();
    if (wave == 0) {
        float r = (part[0][lane] + part[1][lane]) + (part[2][lane] + part[3][lane]);
        v[b * H + h] = r;
    }
}

// ---------------------------------------------------------------------------
// Kernel 2: scores[b,s] = dot(enc[b,s,:], v[b,:])
// grid (S/ROWS_PB, BS) = 8192 blocks, block 256 (4 waves).
// Stage an 8-row (32 KiB) enc tile into LDS via global_load_lds DMA
// (8 calls/wave x 1 KiB, zero dest VGPRs -> ~160 KiB outstanding per CU at
// 5 blocks/CU: HBM-saturating MLP, which the VGPR-bound version could not
// reach — round-5 rocprof: 512 GB/s, occupancy 27%, latency-bound).
// Then wave w computes rows 2w, 2w+1 from LDS (ds_read_b128) + shuffle-reduce.
// Bias omitted: constant per softmax row, cancels in softmax.
// ---------------------------------------------------------------------------
__global__ __launch_bounds__(256) void compute_scores(const float* __restrict__ enc,
                                                      const float* __restrict__ v,
                                                      float* __restrict__ scores) {
    __shared__ float tile[ROWS_PB * H];   // 32 KiB
    const int b    = blockIdx.y;
    const int tid  = threadIdx.x;
    const int wave = tid >> 6;
    const int lane = tid & 63;

    // ---- DMA the tile: linear 32 KiB copy, coalesced, lane*16 per call ----
    const char* gbase = (const char*)(enc + ((size_t)b * S + (size_t)blockIdx.x * ROWS_PB) * H);
    char*       lbase = (char*)tile;
#pragma unroll
    for (int c = 0; c < 8; ++c) {
        const int off = c * 4096 + wave * 1024;   // wave-uniform LDS offset
        load16_to_lds(gbase + off + lane * 16, lbase + off);
    }

    // ---- v fragment (L2-resident) while DMA is in flight ----
    const float4* v4 = (const float4*)(v + b * H);
    float4 vr[4];
#pragma unroll
    for (int it = 0; it < 4; ++it) vr[it] = v4[it * 64 + lane];

    __syncthreads();   // compiler emits s_waitcnt vmcnt(0): tile ready

    // ---- wave w: rows 2w and 2w+1 ----
    const float4* r0 = (const float4*)(tile + (2 * wave) * H);
    const float4* r1 = (const float4*)(tile + (2 * wave + 1) * H);
    float acc0 = 0.f, acc1 = 0.f;
#pragma unroll
    for (int it = 0; it < 4; ++it) {
        float4 e0 = r0[it * 64 + lane];
        float4 e1 = r1[it * 64 + lane];
        acc0 = fmaf(e0.x, vr[it].x, acc0);
        acc0 = fmaf(e0.y, vr[it].y, acc0);
        acc0 = fmaf(e0.z, vr[it].z, acc0);
        acc0 = fmaf(e0.w, vr[it].w, acc0);
        acc1 = fmaf(e1.x, vr[it].x, acc1);
        acc1 = fmaf(e1.y, vr[it].y, acc1);
        acc1 = fmaf(e1.z, vr[it].z, acc1);
        acc1 = fmaf(e1.w, vr[it].w, acc1);
    }
#pragma unroll
    for (int off = 32; off > 0; off >>= 1) {
        acc0 += __shfl_xor(acc0, off, 64);
        acc1 += __shfl_xor(acc1, off, 64);
    }
    if (lane == 0) {
        const int s = blockIdx.x * ROWS_PB + 2 * wave;
        scores[b * S + s]     = acc0;
        scores[b * S + s + 1] = acc1;
    }
}

// ---------------------------------------------------------------------------
// Kernel 3: in-place row softmax on scores (= d_out). grid BS, block 256,
// float4 I/O (2 float4 per thread).
// ---------------------------------------------------------------------------
__global__ __launch_bounds__(256) void softmax_rows(float* __restrict__ scores) {
    const int b    = blockIdx.x;
    const int tid  = threadIdx.x;
    const int wave = tid >> 6;
    const int lane = tid & 63;
    __shared__ float red[4];

    float4* row4 = (float4*)(scores + b * S);
    float4 x[2];
    float m = -INFINITY;
#pragma unroll
    for (int i = 0; i < 2; ++i) {
        x[i] = row4[tid + i * 256];
        m = fmaxf(m, fmaxf(fmaxf(x[i].x, x[i].y), fmaxf(x[i].z, x[i].w)));
    }
#pragma unroll
    for (int off = 1; off < 64; off <<= 1)
        m = fmaxf(m, __shfl_xor(m, off, 64));
    if (lane == 0) red[wave] = m;
    __syncthreads();
    m = fmaxf(fmaxf(red[0], red[1]), fmaxf(red[2], red[3]));

    float sum = 0.f;
#pragma unroll
    for (int i = 0; i < 2; ++i) {
        x[i].x = __expf(x[i].x - m);
        x[i].y = __expf(x[i].y - m);
        x[i].z = __expf(x[i].z - m);
        x[i].w = __expf(x[i].w - m);
        sum += (x[i].x + x[i].y) + (x[i].z + x[i].w);
    }
#pragma unroll
    for (int off = 1; off < 64; off <<= 1)
        sum += __shfl_xor(sum, off, 64);
    __syncthreads();   // red[] reuse
    if (lane == 0) red[wave] = sum;
    __syncthreads();
    sum = (red[0] + red[1]) + (red[2] + red[3]);
    const float inv = 1.0f / sum;

#pragma unroll
    for (int i = 0; i < 2; ++i) {
        x[i].x *= inv; x[i].y *= inv; x[i].z *= inv; x[i].w *= inv;
        row4[tid + i * 256] = x[i];
    }
}

extern "C" void kernel_launch(void* const* d_in, const int* in_sizes, int n_in,
                              void* d_out, int out_size, void* d_ws, size_t ws_size,
                              hipStream_t stream) {
    const float* hidden = (const float*)d_in[0];   // [BS, H]
    const float* enc    = (const float*)d_in[1];   // [BS, S, H]
    const float* W      = (const float*)d_in[2];   // [H, H]
    // d_in[3] = bias: unused — cancels in the softmax.

    float* v    = (float*)d_ws;    // BS*H floats = 128 KiB scratch
    float* outp = (float*)d_out;   // BS*S floats; scores then softmax in place

    dim3 g1(H / 64, BS);
    compute_v<<<g1, 256, 0, stream>>>(hidden, W, v);

    dim3 g2(S / ROWS_PB, BS);
    compute_scores<<<g2, 256, 0, stream>>>(enc, v, outp);

    softmax_rows<<<BS, 256, 0, stream>>>(outp);
}

// Round 8
// 361.686 us; speedup vs baseline: 1.0606x; 1.0606x over previous
//
#include <hip/hip_runtime.h>
#include <math.h>

#define BS 32
#define S  2048
#define H  1024

// native clang vector type — required for __builtin_nontemporal_load
typedef float vfloat4 __attribute__((ext_vector_type(4)));

// ---------------------------------------------------------------------------
// Kernel 1: v[b,h] = sum_k hidden[b,k] * W[k,h]   (v = hidden @ W)
// grid (H/64, BS) = 512 blocks, block 256 = 4 waves.
// Split-k across waves; LDS combine. W (4 MiB) is L2/LLC-resident.
// ---------------------------------------------------------------------------
__global__ __launch_bounds__(256) void compute_v(const float* __restrict__ hidden,
                                                 const float* __restrict__ W,
                                                 float* __restrict__ v) {
    __shared__ float hid[H];
    __shared__ float part[4][64];
    const int b    = blockIdx.y;
    const int tid  = threadIdx.x;
    const int wave = tid >> 6;
    const int lane = tid & 63;

    ((float4*)hid)[tid] = ((const float4*)(hidden + b * H))[tid];
    __syncthreads();

    const int h = blockIdx.x * 64 + lane;
    const float* Wp = W + (size_t)(wave * 256) * H + h;
    const float* hp = hid + wave * 256;
    float acc = 0.f;
#pragma unroll 8
    for (int k = 0; k < 256; ++k)
        acc = fmaf(Wp[(size_t)k * H], hp[k], acc);

    part[wave][lane] = acc;
    __syncthreads();
    if (wave == 0) {
        float r = (part[0][lane] + part[1][lane]) + (part[2][lane] + part[3][lane]);
        v[b * H + h] = r;
    }
}

// ---------------------------------------------------------------------------
// Kernel 2: scores[b,s] = dot(enc[b,s,:], v[b,:])   [round-3 measured best]
// grid (S/64, BS) = 1024 blocks, block 256 (4 waves), 16 rows/wave processed
// in 4 groups of 4 so four shuffle-reduce chains pipeline; nt float4 loads
// (perfectly coalesced, streamed once). v[b,:] held in 16 regs/lane.
// Bias omitted: constant per softmax row, cancels in softmax.
// Measured A/B history: this config 358.7 µs total; 4096-block variant 362.1;
// LDS-DMA variant 383.6; no-nt 8-wide variant 391.9; fused softmax 563.5.
// ---------------------------------------------------------------------------
__global__ __launch_bounds__(256) void compute_scores(const float* __restrict__ enc,
                                                      const float* __restrict__ v,
                                                      float* __restrict__ scores) {
    const int b    = blockIdx.y;
    const int tid  = threadIdx.x;
    const int wave = tid >> 6;
    const int lane = tid & 63;

    const float4* v4 = (const float4*)(v + b * H);
    float4 vr[4];
#pragma unroll
    for (int it = 0; it < 4; ++it) vr[it] = v4[it * 64 + lane];

    const int s0 = blockIdx.x * 64 + wave * 16;
    const vfloat4* encb = (const vfloat4*)enc + (size_t)b * S * (H / 4);

#pragma unroll
    for (int i = 0; i < 16; i += 4) {
        float acc[4] = {0.f, 0.f, 0.f, 0.f};
#pragma unroll
        for (int j = 0; j < 4; ++j) {
            const vfloat4* e4 = encb + (size_t)(s0 + i + j) * (H / 4);
#pragma unroll
            for (int it = 0; it < 4; ++it) {
                vfloat4 e = __builtin_nontemporal_load(&e4[it * 64 + lane]);
                acc[j] = fmaf(e.x, vr[it].x, acc[j]);
                acc[j] = fmaf(e.y, vr[it].y, acc[j]);
                acc[j] = fmaf(e.z, vr[it].z, acc[j]);
                acc[j] = fmaf(e.w, vr[it].w, acc[j]);
            }
        }
        // four independent 64-lane butterfly reductions — chains pipeline
#pragma unroll
        for (int off = 32; off > 0; off >>= 1) {
#pragma unroll
            for (int j = 0; j < 4; ++j)
                acc[j] += __shfl_xor(acc[j], off, 64);
        }
        if (lane < 4)
            scores[b * S + s0 + i + lane] = acc[lane];
    }
}

// ---------------------------------------------------------------------------
// Kernel 3: in-place row softmax on scores (= d_out). grid BS, block 256,
// float4 I/O (2 float4 per thread).
// ---------------------------------------------------------------------------
__global__ __launch_bounds__(256) void softmax_rows(float* __restrict__ scores) {
    const int b    = blockIdx.x;
    const int tid  = threadIdx.x;
    const int wave = tid >> 6;
    const int lane = tid & 63;
    __shared__ float red[4];

    float4* row4 = (float4*)(scores + b * S);
    float4 x[2];
    float m = -INFINITY;
#pragma unroll
    for (int i = 0; i < 2; ++i) {
        x[i] = row4[tid + i * 256];
        m = fmaxf(m, fmaxf(fmaxf(x[i].x, x[i].y), fmaxf(x[i].z, x[i].w)));
    }
#pragma unroll
    for (int off = 1; off < 64; off <<= 1)
        m = fmaxf(m, __shfl_xor(m, off, 64));
    if (lane == 0) red[wave] = m;
    __syncthreads();
    m = fmaxf(fmaxf(red[0], red[1]), fmaxf(red[2], red[3]));

    float sum = 0.f;
#pragma unroll
    for (int i = 0; i < 2; ++i) {
        x[i].x = __expf(x[i].x - m);
        x[i].y = __expf(x[i].y - m);
        x[i].z = __expf(x[i].z - m);
        x[i].w = __expf(x[i].w - m);
        sum += (x[i].x + x[i].y) + (x[i].z + x[i].w);
    }
#pragma unroll
    for (int off = 1; off < 64; off <<= 1)
        sum += __shfl_xor(sum, off, 64);
    __syncthreads();   // red[] reuse
    if (lane == 0) red[wave] = sum;
    __syncthreads();
    sum = (red[0] + red[1]) + (red[2] + red[3]);
    const float inv = 1.0f / sum;

#pragma unroll
    for (int i = 0; i < 2; ++i) {
        x[i].x *= inv; x[i].y *= inv; x[i].z *= inv; x[i].w *= inv;
        row4[tid + i * 256] = x[i];
    }
}

extern "C" void kernel_launch(void* const* d_in, const int* in_sizes, int n_in,
                              void* d_out, int out_size, void* d_ws, size_t ws_size,
                              hipStream_t stream) {
    const float* hidden = (const float*)d_in[0];   // [BS, H]
    const float* enc    = (const float*)d_in[1];   // [BS, S, H]
    const float* W      = (const float*)d_in[2];   // [H, H]
    // d_in[3] = bias: unused — cancels in the softmax.

    float* v    = (float*)d_ws;    // BS*H floats = 128 KiB scratch
    float* outp = (float*)d_out;   // BS*S floats; scores then softmax in place

    dim3 g1(H / 64, BS);
    compute_v<<<g1, 256, 0, stream>>>(hidden, W, v);

    dim3 g2(S / 64, BS);
    compute_scores<<<g2, 256, 0, stream>>>(enc, v, outp);

    softmax_rows<<<BS, 256, 0, stream>>>(outp);
}